// Round 1
// baseline (711.325 us; speedup 1.0000x reference)
//
#include <hip/hip_runtime.h>
#include <hip/hip_bf16.h>

#define NN 8192
#define CFEAT 512
#define NCLS 40
#define NPAD 48
#define INDIM 672
#define HIDD 1024

typedef __attribute__((ext_vector_type(8))) short bf16x8;
typedef __attribute__((ext_vector_type(4))) float f32x4;

__device__ inline unsigned short f2b(float f) {
  union { __hip_bfloat16 b; unsigned short u; } cv;
  cv.b = __float2bfloat16(f);
  return cv.u;
}

// ---------------------------------------------------------------------------
// K1: A_bf16[i][j] = bf16( sigmoid(adj[i][j]) / (rowsum + 1e-8) )
// one block per row; row staged in LDS (32 KB) so adj is read exactly once.
// ---------------------------------------------------------------------------
__global__ __launch_bounds__(256) void normalize_kernel(const float* __restrict__ adj,
                                                        unsigned short* __restrict__ Ab) {
  __shared__ float row[NN];
  __shared__ float wsum[4];
  const int t = threadIdx.x;
  const size_t i = blockIdx.x;
  const float4* src = (const float4*)(adj + i * NN);
  float4* rowv = (float4*)row;
  float sum = 0.f;
#pragma unroll
  for (int it = 0; it < 8; ++it) {
    float4 v = src[it * 256 + t];
    float s0 = 1.f / (1.f + __expf(-v.x));
    float s1 = 1.f / (1.f + __expf(-v.y));
    float s2 = 1.f / (1.f + __expf(-v.z));
    float s3 = 1.f / (1.f + __expf(-v.w));
    rowv[it * 256 + t] = make_float4(s0, s1, s2, s3);
    sum += (s0 + s1) + (s2 + s3);
  }
#pragma unroll
  for (int m = 1; m < 64; m <<= 1) sum += __shfl_xor(sum, m);
  if ((t & 63) == 0) wsum[t >> 6] = sum;
  __syncthreads();
  const float dinv = 1.f / (wsum[0] + wsum[1] + wsum[2] + wsum[3] + 1e-8f);
  ushort4* dst = (ushort4*)(Ab + i * NN);
#pragma unroll
  for (int it = 0; it < 8; ++it) {
    float4 v = rowv[it * 256 + t];
    ushort4 o;
    o.x = f2b(v.x * dinv);
    o.y = f2b(v.y * dinv);
    o.z = f2b(v.z * dinv);
    o.w = f2b(v.w * dinv);
    dst[it * 256 + t] = o;
  }
}

// ---------------------------------------------------------------------------
// prep: X -> combined[:, :512] bf16 ; onehot -> curT0 [48 x 8192] bf16 (transposed);
//       W1 [672x1024] -> W1T [1024x672] bf16 ; W2 [1024x40] -> W2T [48x1024] bf16
// pad rows of curT/W2T are never used for real output columns (masked), so
// they may stay poisoned.
// ---------------------------------------------------------------------------
__global__ __launch_bounds__(256) void prep_kernel(const float* __restrict__ X,
                                                   const float* __restrict__ onehot,
                                                   const float* __restrict__ W1,
                                                   const float* __restrict__ W2,
                                                   unsigned short* __restrict__ comb,
                                                   unsigned short* __restrict__ curT0,
                                                   unsigned short* __restrict__ W1T,
                                                   unsigned short* __restrict__ W2T) {
  const int NX = NN * CFEAT;
  const int NO = NCLS * NN;
  const int NW1 = INDIM * HIDD;
  const int NW2 = HIDD * NCLS;
  const int total = NX + NO + NW1 + NW2;
  for (int idx = blockIdx.x * 256 + threadIdx.x; idx < total; idx += gridDim.x * 256) {
    if (idx < NX) {
      int i = idx >> 9, c = idx & 511;
      comb[(size_t)i * INDIM + c] = f2b(X[idx]);
    } else if (idx < NX + NO) {
      int t = idx - NX;
      int c = t >> 13, i = t & 8191;
      curT0[(size_t)c * NN + i] = f2b(onehot[(size_t)i * NCLS + c]);
    } else if (idx < NX + NO + NW1) {
      int t = idx - NX - NO;
      int k = t >> 10, n = t & 1023;
      W1T[(size_t)n * INDIM + k] = f2b(W1[t]);
    } else {
      int t = idx - NX - NO - NW1;
      int k = t / NCLS, c = t - k * NCLS;
      W2T[(size_t)c * HIDD + k] = f2b(W2[t]);
    }
  }
}

// ---------------------------------------------------------------------------
// hop: next = softmax(A_bf16 @ curT^T) ; writes nextT (transposed, for next hop)
// and the combined[:, 512+hop*40 : +40] section.
// block = 16 output rows, 4 waves split K (2048 each), LDS reduce + softmax.
// MFMA 16x16x32 bf16; A-frag: row=lane&15, k=(lane>>4)*8+j (one 16B load);
// B-frag identical with curT transposed layout. C/D: col=lane&15, row=(lane>>4)*4+r.
// ---------------------------------------------------------------------------
__global__ __launch_bounds__(256) void hop_kernel(const unsigned short* __restrict__ Ab,
                                                  const unsigned short* __restrict__ curT,
                                                  unsigned short* __restrict__ nextT,
                                                  unsigned short* __restrict__ comb,
                                                  int hop) {
  __shared__ float red[4][16][NPAD];
  const int lane = threadIdx.x & 63;
  const int wave = threadIdx.x >> 6;
  const int l15 = lane & 15;
  const int kg = lane >> 4;
  const size_t arow = (size_t)blockIdx.x * 16 + l15;
  const size_t kbase = (size_t)wave * 2048 + (size_t)kg * 8;
  const bf16x8* ap = (const bf16x8*)(Ab + arow * NN + kbase);
  const bf16x8* bp0 = (const bf16x8*)(curT + (size_t)l15 * NN + kbase);
  const bf16x8* bp1 = (const bf16x8*)(curT + (size_t)(16 + l15) * NN + kbase);
  const bf16x8* bp2 = (const bf16x8*)(curT + (size_t)(32 + l15) * NN + kbase);
  f32x4 acc0 = {0.f, 0.f, 0.f, 0.f}, acc1 = {0.f, 0.f, 0.f, 0.f}, acc2 = {0.f, 0.f, 0.f, 0.f};
#pragma unroll 4
  for (int kk = 0; kk < 2048; kk += 32) {
    bf16x8 a = *ap; ap += 4;
    bf16x8 vb0 = *bp0; bp0 += 4;
    bf16x8 vb1 = *bp1; bp1 += 4;
    bf16x8 vb2 = *bp2; bp2 += 4;
    acc0 = __builtin_amdgcn_mfma_f32_16x16x32_bf16(a, vb0, acc0, 0, 0, 0);
    acc1 = __builtin_amdgcn_mfma_f32_16x16x32_bf16(a, vb1, acc1, 0, 0, 0);
    acc2 = __builtin_amdgcn_mfma_f32_16x16x32_bf16(a, vb2, acc2, 0, 0, 0);
  }
#pragma unroll
  for (int r = 0; r < 4; ++r) {
    red[wave][kg * 4 + r][l15] = acc0[r];
    red[wave][kg * 4 + r][16 + l15] = acc1[r];
    red[wave][kg * 4 + r][32 + l15] = acc2[r];
  }
  __syncthreads();
  if (wave == 0) {
#pragma unroll
    for (int r = 0; r < 4; ++r) {
      const int rr = kg * 4 + r;
      float v0 = red[0][rr][l15] + red[1][rr][l15] + red[2][rr][l15] + red[3][rr][l15];
      float v1 = red[0][rr][16 + l15] + red[1][rr][16 + l15] + red[2][rr][16 + l15] + red[3][rr][16 + l15];
      float v2 = red[0][rr][32 + l15] + red[1][rr][32 + l15] + red[2][rr][32 + l15] + red[3][rr][32 + l15];
      const bool ok2 = l15 < 8;  // cols 32..39 valid, 40..47 are padding
      float m = fmaxf(v0, v1);
      if (ok2) m = fmaxf(m, v2);
#pragma unroll
      for (int s = 1; s < 16; s <<= 1) m = fmaxf(m, __shfl_xor(m, s));
      float e0 = __expf(v0 - m);
      float e1 = __expf(v1 - m);
      float e2 = ok2 ? __expf(v2 - m) : 0.f;
      float ssum = e0 + e1 + e2;
#pragma unroll
      for (int s = 1; s < 16; s <<= 1) ssum += __shfl_xor(ssum, s);
      const float inv = 1.f / ssum;
      const size_t i = (size_t)blockIdx.x * 16 + rr;
      const unsigned short p0 = f2b(e0 * inv);
      const unsigned short p1 = f2b(e1 * inv);
      nextT[(size_t)l15 * NN + i] = p0;
      nextT[(size_t)(16 + l15) * NN + i] = p1;
      const size_t cbase = i * INDIM + CFEAT + (size_t)hop * NCLS;
      comb[cbase + l15] = p0;
      comb[cbase + 16 + l15] = p1;
      if (ok2) {
        const unsigned short p2 = f2b(e2 * inv);
        nextT[(size_t)(32 + l15) * NN + i] = p2;
        comb[cbase + 32 + l15] = p2;
      }
    }
  }
}

// ---------------------------------------------------------------------------
// GEMM1: h = relu(combined @ W1 + b1), bf16 out. tile 64(M) x 128(N), 4 waves.
// ---------------------------------------------------------------------------
__global__ __launch_bounds__(256) void gemm1_kernel(const unsigned short* __restrict__ comb,
                                                    const unsigned short* __restrict__ W1T,
                                                    const float* __restrict__ bias1,
                                                    unsigned short* __restrict__ h) {
  const int lane = threadIdx.x & 63;
  const int wave = threadIdx.x >> 6;
  const int l15 = lane & 15;
  const int kg = lane >> 4;
  const int bm = blockIdx.x & 127;
  const int bn = blockIdx.x >> 7;
  const size_t arow = (size_t)bm * 64 + wave * 16 + l15;
  const bf16x8* ap = (const bf16x8*)(comb + arow * INDIM + (size_t)kg * 8);
  const bf16x8* bp[8];
#pragma unroll
  for (int tt = 0; tt < 8; ++tt)
    bp[tt] = (const bf16x8*)(W1T + (size_t)(bn * 128 + tt * 16 + l15) * INDIM + (size_t)kg * 8);
  f32x4 acc[8] = {};
#pragma unroll 3
  for (int kk = 0; kk < INDIM; kk += 32) {
    bf16x8 a = *ap; ap += 4;
#pragma unroll
    for (int tt = 0; tt < 8; ++tt) {
      bf16x8 b = *bp[tt]; bp[tt] += 4;
      acc[tt] = __builtin_amdgcn_mfma_f32_16x16x32_bf16(a, b, acc[tt], 0, 0, 0);
    }
  }
#pragma unroll
  for (int tt = 0; tt < 8; ++tt) {
    const int n = bn * 128 + tt * 16 + l15;
    const float bv = bias1[n];
#pragma unroll
    for (int r = 0; r < 4; ++r) {
      const size_t i = (size_t)bm * 64 + wave * 16 + kg * 4 + r;
      float v = acc[tt][r] + bv;
      h[i * HIDD + n] = f2b(v > 0.f ? v : 0.f);
    }
  }
}

// ---------------------------------------------------------------------------
// GEMM2: out = h @ W2 + b2 (fp32 out). same structure as hop, no softmax.
// ---------------------------------------------------------------------------
__global__ __launch_bounds__(256) void gemm2_kernel(const unsigned short* __restrict__ h,
                                                    const unsigned short* __restrict__ W2T,
                                                    const float* __restrict__ bias2,
                                                    float* __restrict__ out) {
  __shared__ float red[4][16][NPAD];
  const int lane = threadIdx.x & 63;
  const int wave = threadIdx.x >> 6;
  const int l15 = lane & 15;
  const int kg = lane >> 4;
  const size_t arow = (size_t)blockIdx.x * 16 + l15;
  const size_t kbase = (size_t)wave * 256 + (size_t)kg * 8;
  const bf16x8* ap = (const bf16x8*)(h + arow * HIDD + kbase);
  const bf16x8* bp0 = (const bf16x8*)(W2T + (size_t)l15 * HIDD + kbase);
  const bf16x8* bp1 = (const bf16x8*)(W2T + (size_t)(16 + l15) * HIDD + kbase);
  const bf16x8* bp2 = (const bf16x8*)(W2T + (size_t)(32 + l15) * HIDD + kbase);
  f32x4 acc0 = {0.f, 0.f, 0.f, 0.f}, acc1 = {0.f, 0.f, 0.f, 0.f}, acc2 = {0.f, 0.f, 0.f, 0.f};
#pragma unroll
  for (int kk = 0; kk < 256; kk += 32) {
    bf16x8 a = *ap; ap += 4;
    bf16x8 vb0 = *bp0; bp0 += 4;
    bf16x8 vb1 = *bp1; bp1 += 4;
    bf16x8 vb2 = *bp2; bp2 += 4;
    acc0 = __builtin_amdgcn_mfma_f32_16x16x32_bf16(a, vb0, acc0, 0, 0, 0);
    acc1 = __builtin_amdgcn_mfma_f32_16x16x32_bf16(a, vb1, acc1, 0, 0, 0);
    acc2 = __builtin_amdgcn_mfma_f32_16x16x32_bf16(a, vb2, acc2, 0, 0, 0);
  }
#pragma unroll
  for (int r = 0; r < 4; ++r) {
    red[wave][kg * 4 + r][l15] = acc0[r];
    red[wave][kg * 4 + r][16 + l15] = acc1[r];
    red[wave][kg * 4 + r][32 + l15] = acc2[r];
  }
  __syncthreads();
  if (wave == 0) {
#pragma unroll
    for (int r = 0; r < 4; ++r) {
      const int rr = kg * 4 + r;
      float v0 = red[0][rr][l15] + red[1][rr][l15] + red[2][rr][l15] + red[3][rr][l15];
      float v1 = red[0][rr][16 + l15] + red[1][rr][16 + l15] + red[2][rr][16 + l15] + red[3][rr][16 + l15];
      float v2 = red[0][rr][32 + l15] + red[1][rr][32 + l15] + red[2][rr][32 + l15] + red[3][rr][32 + l15];
      const size_t i = (size_t)blockIdx.x * 16 + rr;
      out[i * NCLS + l15] = v0 + bias2[l15];
      out[i * NCLS + 16 + l15] = v1 + bias2[16 + l15];
      if (l15 < 8) out[i * NCLS + 32 + l15] = v2 + bias2[32 + l15];
    }
  }
}

extern "C" void kernel_launch(void* const* d_in, const int* in_sizes, int n_in,
                              void* d_out, int out_size, void* d_ws, size_t ws_size,
                              hipStream_t stream) {
  const float* X = (const float*)d_in[0];
  const float* onehot = (const float*)d_in[1];
  const float* adj = (const float*)d_in[2];
  const float* W1 = (const float*)d_in[3];
  const float* b1 = (const float*)d_in[4];
  const float* W2 = (const float*)d_in[5];
  const float* b2 = (const float*)d_in[6];
  float* out = (float*)d_out;
  char* ws = (char*)d_ws;

  // workspace layout (bytes)
  unsigned short* Ab   = (unsigned short*)(ws);                 // 8192*8192*2   = 134217728
  unsigned short* cur0 = (unsigned short*)(ws + 134217728ull);  // 48*8192*2     = 786432
  unsigned short* cur1 = (unsigned short*)(ws + 135004160ull);  // 48*8192*2     = 786432
  unsigned short* comb = (unsigned short*)(ws + 135790592ull);  // 8192*672*2    = 11010048
  unsigned short* W1T  = (unsigned short*)(ws + 146800640ull);  // 1024*672*2    = 1376256
  unsigned short* W2T  = (unsigned short*)(ws + 148176896ull);  // 48*1024*2     = 98304
  unsigned short* hbuf = (unsigned short*)(ws + 148275200ull);  // 8192*1024*2   = 16777216
  // total = 165052416 bytes

  normalize_kernel<<<NN, 256, 0, stream>>>(adj, Ab);
  prep_kernel<<<2048, 256, 0, stream>>>(X, onehot, W1, W2, comb, cur0, W1T, W2T);
  hop_kernel<<<NN / 16, 256, 0, stream>>>(Ab, cur0, cur1, comb, 0);
  hop_kernel<<<NN / 16, 256, 0, stream>>>(Ab, cur1, cur0, comb, 1);
  hop_kernel<<<NN / 16, 256, 0, stream>>>(Ab, cur0, cur1, comb, 2);
  hop_kernel<<<NN / 16, 256, 0, stream>>>(Ab, cur1, cur0, comb, 3);
  gemm1_kernel<<<1024, 256, 0, stream>>>(comb, W1T, b1, hbuf);
  gemm2_kernel<<<NN / 16, 256, 0, stream>>>(hbuf, W2T, b2, out);
}

// Round 2
// 694.885 us; speedup vs baseline: 1.0237x; 1.0237x over previous
//
#include <hip/hip_runtime.h>
#include <hip/hip_bf16.h>

#define NN 8192
#define CFEAT 512
#define NCLS 40
#define NPAD 48
#define INDIM 672
#define HIDD 1024

typedef __attribute__((ext_vector_type(8))) short bf16x8;
typedef __attribute__((ext_vector_type(4))) float f32x4;

#define A_SCALE 1048576.0f        // 2^20
#define A_INV_SCALE 9.5367431640625e-07f  // 2^-20

__device__ inline unsigned short f2b(float f) {
  union { __hip_bfloat16 b; unsigned short u; } cv;
  cv.b = __float2bfloat16(f);
  return cv.u;
}

__device__ inline unsigned char f2fp8(float f) {
  int pk = __builtin_amdgcn_cvt_pk_fp8_f32(f, 0.f, 0, false);
  return (unsigned char)(pk & 0xff);
}

// ---------------------------------------------------------------------------
// K1: A8[i][j] = fp8_e4m3( 2^20 * sigmoid(adj[i][j]) / (rowsum + 1e-8) )
// one block per row; sigmoid row kept in 32 VGPRs (no LDS round trip).
// entries*2^20 land in [~2, 256] -- all normal-range e4m3.
// ---------------------------------------------------------------------------
__global__ __launch_bounds__(256) void normalize_kernel(const float* __restrict__ adj,
                                                        unsigned char* __restrict__ A8) {
  __shared__ float wsum[4];
  const int t = threadIdx.x;
  const size_t i = blockIdx.x;
  const float4* src = (const float4*)(adj + i * NN);
  float4 v[8];
  float sum = 0.f;
#pragma unroll
  for (int it = 0; it < 8; ++it) {
    float4 x = src[it * 256 + t];
    float s0 = 1.f / (1.f + __expf(-x.x));
    float s1 = 1.f / (1.f + __expf(-x.y));
    float s2 = 1.f / (1.f + __expf(-x.z));
    float s3 = 1.f / (1.f + __expf(-x.w));
    v[it] = make_float4(s0, s1, s2, s3);
    sum += (s0 + s1) + (s2 + s3);
  }
#pragma unroll
  for (int m = 1; m < 64; m <<= 1) sum += __shfl_xor(sum, m);
  if ((t & 63) == 0) wsum[t >> 6] = sum;
  __syncthreads();
  const float dinv = A_SCALE / (wsum[0] + wsum[1] + wsum[2] + wsum[3] + 1e-8f);
  unsigned int* dst = (unsigned int*)(A8 + i * NN);
#pragma unroll
  for (int it = 0; it < 8; ++it) {
    int lo = __builtin_amdgcn_cvt_pk_fp8_f32(v[it].x * dinv, v[it].y * dinv, 0, false);
    int pk = __builtin_amdgcn_cvt_pk_fp8_f32(v[it].z * dinv, v[it].w * dinv, lo, true);
    dst[it * 256 + t] = (unsigned int)pk;
  }
}

// ---------------------------------------------------------------------------
// prep: X -> combined[:, :512] bf16 ; onehot -> curT0 [48 x 8192] fp8 (transposed);
//       W1 -> W1T bf16 ; W2 -> W2T bf16. pad rows of curT/W2T stay poisoned
//       (finite in e4m3fn/bf16, masked downstream).
// ---------------------------------------------------------------------------
__global__ __launch_bounds__(256) void prep_kernel(const float* __restrict__ X,
                                                   const float* __restrict__ onehot,
                                                   const float* __restrict__ W1,
                                                   const float* __restrict__ W2,
                                                   unsigned short* __restrict__ comb,
                                                   unsigned char* __restrict__ curT0,
                                                   unsigned short* __restrict__ W1T,
                                                   unsigned short* __restrict__ W2T) {
  const int NX = NN * CFEAT;
  const int NO = NCLS * NN;
  const int NW1 = INDIM * HIDD;
  const int NW2 = HIDD * NCLS;
  const int total = NX + NO + NW1 + NW2;
  for (int idx = blockIdx.x * 256 + threadIdx.x; idx < total; idx += gridDim.x * 256) {
    if (idx < NX) {
      int i = idx >> 9, c = idx & 511;
      comb[(size_t)i * INDIM + c] = f2b(X[idx]);
    } else if (idx < NX + NO) {
      int t = idx - NX;
      int c = t >> 13, i = t & 8191;
      curT0[(size_t)c * NN + i] = f2fp8(onehot[(size_t)i * NCLS + c]);
    } else if (idx < NX + NO + NW1) {
      int t = idx - NX - NO;
      int k = t >> 10, n = t & 1023;
      W1T[(size_t)n * INDIM + k] = f2b(W1[t]);
    } else {
      int t = idx - NX - NO - NW1;
      int k = t / NCLS, c = t - k * NCLS;
      W2T[(size_t)c * HIDD + k] = f2b(W2[t]);
    }
  }
}

// ---------------------------------------------------------------------------
// hop: next = softmax((A8 @ curT^T) * 2^-20) ; fp8 MFMA 16x16x32.
// block = 16 output rows, 8 waves split K (1024 each), LDS reduce + softmax.
// A-frag: row=lane&15, k=(lane>>4)*8+j (one 8B load); B-frag same on curT rows.
// C/D: col=lane&15, row=(lane>>4)*4+r.
// ---------------------------------------------------------------------------
__global__ __launch_bounds__(512) void hop_kernel(const unsigned char* __restrict__ A8,
                                                  const unsigned char* __restrict__ curT,
                                                  unsigned char* __restrict__ nextT,
                                                  unsigned short* __restrict__ comb,
                                                  int hop) {
  __shared__ float red[8][16][NPAD];
  const int lane = threadIdx.x & 63;
  const int wave = threadIdx.x >> 6;
  const int l15 = lane & 15;
  const int kg = lane >> 4;
  const size_t arow = (size_t)blockIdx.x * 16 + l15;
  const size_t kbase = (size_t)wave * 1024 + (size_t)kg * 8;
  const long* ap = (const long*)(A8 + arow * NN + kbase);
  const long* bp0 = (const long*)(curT + (size_t)l15 * NN + kbase);
  const long* bp1 = (const long*)(curT + (size_t)(16 + l15) * NN + kbase);
  const long* bp2 = (const long*)(curT + (size_t)(32 + l15) * NN + kbase);
  f32x4 acc0 = {0.f, 0.f, 0.f, 0.f}, acc1 = {0.f, 0.f, 0.f, 0.f}, acc2 = {0.f, 0.f, 0.f, 0.f};
#pragma unroll 4
  for (int kk = 0; kk < 1024; kk += 32) {
    long a = *ap; ap += 4;
    long b0 = *bp0; bp0 += 4;
    long b1 = *bp1; bp1 += 4;
    long b2 = *bp2; bp2 += 4;
    acc0 = __builtin_amdgcn_mfma_f32_16x16x32_fp8_fp8(a, b0, acc0, 0, 0, 0);
    acc1 = __builtin_amdgcn_mfma_f32_16x16x32_fp8_fp8(a, b1, acc1, 0, 0, 0);
    acc2 = __builtin_amdgcn_mfma_f32_16x16x32_fp8_fp8(a, b2, acc2, 0, 0, 0);
  }
#pragma unroll
  for (int r = 0; r < 4; ++r) {
    red[wave][kg * 4 + r][l15] = acc0[r];
    red[wave][kg * 4 + r][16 + l15] = acc1[r];
    red[wave][kg * 4 + r][32 + l15] = acc2[r];
  }
  __syncthreads();
  if (wave == 0) {
#pragma unroll
    for (int r = 0; r < 4; ++r) {
      const int rr = kg * 4 + r;
      float v0 = 0.f, v1 = 0.f, v2 = 0.f;
#pragma unroll
      for (int w = 0; w < 8; ++w) {
        v0 += red[w][rr][l15];
        v1 += red[w][rr][16 + l15];
        v2 += red[w][rr][32 + l15];
      }
      v0 *= A_INV_SCALE; v1 *= A_INV_SCALE; v2 *= A_INV_SCALE;
      const bool ok2 = l15 < 8;  // cols 32..39 valid, 40..47 are padding
      float m = fmaxf(v0, v1);
      if (ok2) m = fmaxf(m, v2);
#pragma unroll
      for (int s = 1; s < 16; s <<= 1) m = fmaxf(m, __shfl_xor(m, s));
      float e0 = __expf(v0 - m);
      float e1 = __expf(v1 - m);
      float e2 = ok2 ? __expf(v2 - m) : 0.f;
      float ssum = e0 + e1 + e2;
#pragma unroll
      for (int s = 1; s < 16; s <<= 1) ssum += __shfl_xor(ssum, s);
      const float inv = 1.f / ssum;
      const size_t i = (size_t)blockIdx.x * 16 + rr;
      const float p0 = e0 * inv;
      const float p1 = e1 * inv;
      nextT[(size_t)l15 * NN + i] = f2fp8(p0);
      nextT[(size_t)(16 + l15) * NN + i] = f2fp8(p1);
      const size_t cbase = i * INDIM + CFEAT + (size_t)hop * NCLS;
      comb[cbase + l15] = f2b(p0);
      comb[cbase + 16 + l15] = f2b(p1);
      if (ok2) {
        const float p2 = e2 * inv;
        nextT[(size_t)(32 + l15) * NN + i] = f2fp8(p2);
        comb[cbase + 32 + l15] = f2b(p2);
      }
    }
  }
}

// ---------------------------------------------------------------------------
// GEMM1: h = relu(combined @ W1 + b1), bf16 out. tile 64(M) x 128(N), 4 waves.
// ---------------------------------------------------------------------------
__global__ __launch_bounds__(256) void gemm1_kernel(const unsigned short* __restrict__ comb,
                                                    const unsigned short* __restrict__ W1T,
                                                    const float* __restrict__ bias1,
                                                    unsigned short* __restrict__ h) {
  const int lane = threadIdx.x & 63;
  const int wave = threadIdx.x >> 6;
  const int l15 = lane & 15;
  const int kg = lane >> 4;
  const int bm = blockIdx.x & 127;
  const int bn = blockIdx.x >> 7;
  const size_t arow = (size_t)bm * 64 + wave * 16 + l15;
  const bf16x8* ap = (const bf16x8*)(comb + arow * INDIM + (size_t)kg * 8);
  const bf16x8* bp[8];
#pragma unroll
  for (int tt = 0; tt < 8; ++tt)
    bp[tt] = (const bf16x8*)(W1T + (size_t)(bn * 128 + tt * 16 + l15) * INDIM + (size_t)kg * 8);
  f32x4 acc[8] = {};
#pragma unroll 3
  for (int kk = 0; kk < INDIM; kk += 32) {
    bf16x8 a = *ap; ap += 4;
#pragma unroll
    for (int tt = 0; tt < 8; ++tt) {
      bf16x8 b = *bp[tt]; bp[tt] += 4;
      acc[tt] = __builtin_amdgcn_mfma_f32_16x16x32_bf16(a, b, acc[tt], 0, 0, 0);
    }
  }
#pragma unroll
  for (int tt = 0; tt < 8; ++tt) {
    const int n = bn * 128 + tt * 16 + l15;
    const float bv = bias1[n];
#pragma unroll
    for (int r = 0; r < 4; ++r) {
      const size_t i = (size_t)bm * 64 + wave * 16 + kg * 4 + r;
      float v = acc[tt][r] + bv;
      h[i * HIDD + n] = f2b(v > 0.f ? v : 0.f);
    }
  }
}

// ---------------------------------------------------------------------------
// GEMM2: out = h @ W2 + b2 (fp32 out). bf16 MFMA, 4-wave K-split + LDS reduce.
// ---------------------------------------------------------------------------
__global__ __launch_bounds__(256) void gemm2_kernel(const unsigned short* __restrict__ h,
                                                    const unsigned short* __restrict__ W2T,
                                                    const float* __restrict__ bias2,
                                                    float* __restrict__ out) {
  __shared__ float red[4][16][NPAD];
  const int lane = threadIdx.x & 63;
  const int wave = threadIdx.x >> 6;
  const int l15 = lane & 15;
  const int kg = lane >> 4;
  const size_t arow = (size_t)blockIdx.x * 16 + l15;
  const size_t kbase = (size_t)wave * 256 + (size_t)kg * 8;
  const bf16x8* ap = (const bf16x8*)(h + arow * HIDD + kbase);
  const bf16x8* bp0 = (const bf16x8*)(W2T + (size_t)l15 * HIDD + kbase);
  const bf16x8* bp1 = (const bf16x8*)(W2T + (size_t)(16 + l15) * HIDD + kbase);
  const bf16x8* bp2 = (const bf16x8*)(W2T + (size_t)(32 + l15) * HIDD + kbase);
  f32x4 acc0 = {0.f, 0.f, 0.f, 0.f}, acc1 = {0.f, 0.f, 0.f, 0.f}, acc2 = {0.f, 0.f, 0.f, 0.f};
#pragma unroll
  for (int kk = 0; kk < 256; kk += 32) {
    bf16x8 a = *ap; ap += 4;
    bf16x8 vb0 = *bp0; bp0 += 4;
    bf16x8 vb1 = *bp1; bp1 += 4;
    bf16x8 vb2 = *bp2; bp2 += 4;
    acc0 = __builtin_amdgcn_mfma_f32_16x16x32_bf16(a, vb0, acc0, 0, 0, 0);
    acc1 = __builtin_amdgcn_mfma_f32_16x16x32_bf16(a, vb1, acc1, 0, 0, 0);
    acc2 = __builtin_amdgcn_mfma_f32_16x16x32_bf16(a, vb2, acc2, 0, 0, 0);
  }
#pragma unroll
  for (int r = 0; r < 4; ++r) {
    red[wave][kg * 4 + r][l15] = acc0[r];
    red[wave][kg * 4 + r][16 + l15] = acc1[r];
    red[wave][kg * 4 + r][32 + l15] = acc2[r];
  }
  __syncthreads();
  if (wave == 0) {
#pragma unroll
    for (int r = 0; r < 4; ++r) {
      const int rr = kg * 4 + r;
      float v0 = red[0][rr][l15] + red[1][rr][l15] + red[2][rr][l15] + red[3][rr][l15];
      float v1 = red[0][rr][16 + l15] + red[1][rr][16 + l15] + red[2][rr][16 + l15] + red[3][rr][16 + l15];
      float v2 = red[0][rr][32 + l15] + red[1][rr][32 + l15] + red[2][rr][32 + l15] + red[3][rr][32 + l15];
      const size_t i = (size_t)blockIdx.x * 16 + rr;
      out[i * NCLS + l15] = v0 + bias2[l15];
      out[i * NCLS + 16 + l15] = v1 + bias2[16 + l15];
      if (l15 < 8) out[i * NCLS + 32 + l15] = v2 + bias2[32 + l15];
    }
  }
}

extern "C" void kernel_launch(void* const* d_in, const int* in_sizes, int n_in,
                              void* d_out, int out_size, void* d_ws, size_t ws_size,
                              hipStream_t stream) {
  const float* X = (const float*)d_in[0];
  const float* onehot = (const float*)d_in[1];
  const float* adj = (const float*)d_in[2];
  const float* W1 = (const float*)d_in[3];
  const float* b1 = (const float*)d_in[4];
  const float* W2 = (const float*)d_in[5];
  const float* b2 = (const float*)d_in[6];
  float* out = (float*)d_out;
  char* ws = (char*)d_ws;

  // workspace layout (bytes)
  unsigned char*  A8   = (unsigned char*)(ws);                 // 8192*8192*1   = 67108864
  unsigned char*  cur0 = (unsigned char*)(ws + 67108864ull);   // 48*8192*1     = 393216
  unsigned char*  cur1 = (unsigned char*)(ws + 67502080ull);   // 48*8192*1     = 393216
  unsigned short* comb = (unsigned short*)(ws + 67895296ull);  // 8192*672*2    = 11010048
  unsigned short* W1T  = (unsigned short*)(ws + 78905344ull);  // 1024*672*2    = 1376256
  unsigned short* W2T  = (unsigned short*)(ws + 80281600ull);  // 48*1024*2     = 98304
  unsigned short* hbuf = (unsigned short*)(ws + 80379904ull);  // 8192*1024*2   = 16777216
  // total = 97157120 bytes

  normalize_kernel<<<NN, 256, 0, stream>>>(adj, A8);
  prep_kernel<<<2048, 256, 0, stream>>>(X, onehot, W1, W2, comb, cur0, W1T, W2T);
  hop_kernel<<<NN / 16, 512, 0, stream>>>(A8, cur0, cur1, comb, 0);
  hop_kernel<<<NN / 16, 512, 0, stream>>>(A8, cur1, cur0, comb, 1);
  hop_kernel<<<NN / 16, 512, 0, stream>>>(A8, cur0, cur1, comb, 2);
  hop_kernel<<<NN / 16, 512, 0, stream>>>(A8, cur1, cur0, comb, 3);
  gemm1_kernel<<<1024, 256, 0, stream>>>(comb, W1T, b1, hbuf);
  gemm2_kernel<<<NN / 16, 256, 0, stream>>>(hbuf, W2T, b2, out);
}